// Round 10
// baseline (932.186 us; speedup 1.0000x reference)
//
#include <hip/hip_runtime.h>

#define DEVFN __device__ __forceinline__

namespace {

constexpr int NN = 50000;   // nodes
constexpr int NE = 600000;  // edges
constexpr int H  = 128;
constexpr float LN_EPS = 1e-6f;

typedef _Float16 f16x8 __attribute__((ext_vector_type(8)));
typedef _Float16 f16x4 __attribute__((ext_vector_type(4)));
typedef float f32x4 __attribute__((ext_vector_type(4)));

// acc[8][4] += xs_tile(8 rows x K) @ W(K x 128) restricted to cols c0..c0+3.
DEVFN void mm_block(const float* xsrow, int pitch, int K,
                    const float* __restrict__ W, int c0, float (&acc)[8][4]) {
  for (int k = 0; k < K; k += 4) {
    float4 w0 = *(const float4*)(W + (size_t)(k + 0) * H + c0);
    float4 w1 = *(const float4*)(W + (size_t)(k + 1) * H + c0);
    float4 w2 = *(const float4*)(W + (size_t)(k + 2) * H + c0);
    float4 w3 = *(const float4*)(W + (size_t)(k + 3) * H + c0);
#pragma unroll
    for (int r = 0; r < 8; ++r) {
      float4 a = *(const float4*)(xsrow + r * pitch + k);
      acc[r][0] += a.x * w0.x; acc[r][0] += a.y * w1.x; acc[r][0] += a.z * w2.x; acc[r][0] += a.w * w3.x;
      acc[r][1] += a.x * w0.y; acc[r][1] += a.y * w1.y; acc[r][1] += a.z * w2.y; acc[r][1] += a.w * w3.y;
      acc[r][2] += a.x * w0.z; acc[r][2] += a.y * w1.z; acc[r][2] += a.z * w2.z; acc[r][2] += a.w * w3.z;
      acc[r][3] += a.x * w0.w; acc[r][3] += a.y * w1.w; acc[r][3] += a.z * w2.w; acc[r][3] += a.w * w3.w;
    }
  }
}

// shared fp32 linear body: y[r0..r0+32) = x @ W  (K=128, N=128)
DEVFN void linear_body(const float* __restrict__ x, const float* __restrict__ W,
                       float* __restrict__ y, int r0, int R, int t, float* xs) {
  {
    const int r = t & 31, q = t >> 5;
    int row = r0 + r;
    if (row >= R) row = R - 1;
    const float* src = &x[(size_t)row * H + q * 32];
#pragma unroll
    for (int j = 0; j < 8; ++j)
      *(float4*)&xs[r * 132 + q * 32 + j * 4] = *(const float4*)&src[j * 4];
  }
  __syncthreads();
  const int c0 = (t & 31) * 4;
  const int rbase = (t >> 5) * 8;
  float acc[8][4];
#pragma unroll
  for (int r = 0; r < 8; ++r) { acc[r][0] = 0.f; acc[r][1] = 0.f; acc[r][2] = 0.f; acc[r][3] = 0.f; }
  mm_block(&xs[rbase * 132], 132, H, W, c0, acc);
#pragma unroll
  for (int r = 0; r < 8; ++r) {
    int row = r0 + rbase + r;
    if (row < R)
      *(float4*)&y[(size_t)row * H + c0] =
          make_float4(acc[r][0], acc[r][1], acc[r][2], acc[r][3]);
  }
}

// ---------------- node encoder (2-layer MLP, ReLU between), fp16 out ----------------
template <int K_IN>
__global__ __launch_bounds__(128) void encoder_kernel(
    const float* __restrict__ x, const float* __restrict__ W0,
    const float* __restrict__ b0, const float* __restrict__ W1,
    const float* __restrict__ b1, _Float16* __restrict__ outp, int R) {
  constexpr int PIN = K_IN + 4;
  __shared__ float xs[32 * PIN];
  __shared__ float hs[32 * 132];
  const int t = threadIdx.x;
  const int r0 = blockIdx.x * 32;

  const int nvec = 32 * K_IN / 4;
  for (int i = t; i < nvec; i += 128) {
    int rr = i / (K_IN / 4);
    int kk = (i % (K_IN / 4)) * 4;
    int row = r0 + rr;
    float4 v = make_float4(0.f, 0.f, 0.f, 0.f);
    if (row < R) v = *(const float4*)&x[(size_t)row * K_IN + kk];
    *(float4*)&xs[rr * PIN + kk] = v;
  }
  __syncthreads();

  const int c0 = (t & 31) * 4;
  const int rbase = (t >> 5) * 8;
  float acc[8][4];
  {
    float4 bb = *(const float4*)&b0[c0];
#pragma unroll
    for (int r = 0; r < 8; ++r) { acc[r][0] = bb.x; acc[r][1] = bb.y; acc[r][2] = bb.z; acc[r][3] = bb.w; }
  }
  mm_block(&xs[rbase * PIN], PIN, K_IN, W0, c0, acc);
#pragma unroll
  for (int r = 0; r < 8; ++r) {
    float4 h;
    h.x = fmaxf(acc[r][0], 0.f); h.y = fmaxf(acc[r][1], 0.f);
    h.z = fmaxf(acc[r][2], 0.f); h.w = fmaxf(acc[r][3], 0.f);
    *(float4*)&hs[(rbase + r) * 132 + c0] = h;
  }
  __syncthreads();
  {
    float4 bb = *(const float4*)&b1[c0];
#pragma unroll
    for (int r = 0; r < 8; ++r) { acc[r][0] = bb.x; acc[r][1] = bb.y; acc[r][2] = bb.z; acc[r][3] = bb.w; }
  }
  mm_block(&hs[rbase * 132], 132, H, W1, c0, acc);
#pragma unroll
  for (int r = 0; r < 8; ++r) {
    int row = r0 + rbase + r;
    if (row < R) {
      f16x4 pk = {(_Float16)acc[r][0], (_Float16)acc[r][1],
                  (_Float16)acc[r][2], (_Float16)acc[r][3]};
      *(f16x4*)&outp[(size_t)row * H + c0] = pk;
    }
  }
}

// ---------------- fold stage 1: T = Wb@W0b (blocks 0-3), Wf = Wt@W0b (blocks 4-7) ----------------
__global__ __launch_bounds__(128) void fold1_kernel(
    const float* __restrict__ Wb, const float* __restrict__ Wt,
    const float* __restrict__ W0b, float* __restrict__ T,
    float* __restrict__ Wf) {
  __shared__ float xs[32 * 132];
  const float* x = (blockIdx.x < 4) ? Wb : Wt;
  float* y = (blockIdx.x < 4) ? T : Wf;
  linear_body(x, W0b, y, (blockIdx.x & 3) * 32, 128, threadIdx.x, xs);
}

// ---------------- fold stage 2: Wc2 = W1e@T (blocks 0-3), bc2 = b1e@T (block 4) ----------------
__global__ __launch_bounds__(128) void fold2_kernel(
    const float* __restrict__ W1e, const float* __restrict__ b1e,
    const float* __restrict__ T, float* __restrict__ Wc2,
    float* __restrict__ bc2) {
  __shared__ float xs[32 * 132];
  if (blockIdx.x < 4) {
    linear_body(W1e, T, Wc2, blockIdx.x * 32, 128, threadIdx.x, xs);
  } else {
    int j = threadIdx.x;
    float s = 0.f;
    for (int k = 0; k < H; ++k) s += b1e[k] * T[(size_t)k * H + j];
    bc2[j] = s;
  }
}

// ---------------- prepack 4 weight matrices -> MFMA B-fragment order, fp16 ----------------
// z: 0=W0t(node_W0 rows0-127), 1=Wf32, 2=node_W1, 3=W_node; dst contiguous.
__global__ __launch_bounds__(64) void prepack4_kernel(
    const float* __restrict__ s0, const float* __restrict__ s1,
    const float* __restrict__ s2, const float* __restrict__ s3,
    _Float16* __restrict__ pkBase) {
  const int z = blockIdx.z;
  const float* W = (z == 0) ? s0 : (z == 1) ? s1 : (z == 2) ? s2 : s3;
  _Float16* pk = pkBase + (size_t)z * 128 * H;
  const int ks = blockIdx.x, ct = blockIdx.y, l = threadIdx.x;
  const int kbase = ks * 32 + (l >> 4) * 8;
  const int col = ct * 16 + (l & 15);
  _Float16 tmp[8];
#pragma unroll
  for (int j = 0; j < 8; ++j)
    tmp[j] = (_Float16)W[(size_t)(kbase + j) * H + col];
  *(f16x8*)&pk[((size_t)((ks * 8 + ct) * 64) + l) * 8] = *(f16x8*)tmp;
}

// ---------------- counting sort by receiver ----------------
__global__ __launch_bounds__(256) void hist_kernel(const int* __restrict__ recv,
                                                   int* __restrict__ cnt) {
  int i = blockIdx.x * 256 + threadIdx.x;
  if (i < NE) atomicAdd(&cnt[recv[i]], 1);
}

__global__ __launch_bounds__(256) void scan1_kernel(const int* __restrict__ cnt,
                                                    int* __restrict__ excl,
                                                    int* __restrict__ part) {
  __shared__ int s[256];
  int t = threadIdx.x;
  int i = blockIdx.x * 256 + t;
  int v = (i < NN) ? cnt[i] : 0;
  s[t] = v;
  __syncthreads();
  for (int off = 1; off < 256; off <<= 1) {
    int x = (t >= off) ? s[t - off] : 0;
    __syncthreads();
    s[t] += x;
    __syncthreads();
  }
  if (i < NN) excl[i] = s[t] - v;
  if (t == 255) part[blockIdx.x] = s[255];
}

__global__ __launch_bounds__(256) void scan2_kernel(int* __restrict__ part, int nb) {
  __shared__ int s[256];
  int t = threadIdx.x;
  int v = (t < nb) ? part[t] : 0;
  s[t] = v;
  __syncthreads();
  for (int off = 1; off < 256; off <<= 1) {
    int x = (t >= off) ? s[t - off] : 0;
    __syncthreads();
    s[t] += x;
    __syncthreads();
  }
  if (t < nb) part[t] = s[t] - v;
}

__global__ __launch_bounds__(256) void scan3_kernel(int* __restrict__ excl,
                                                    const int* __restrict__ part,
                                                    int* __restrict__ cursor) {
  int i = blockIdx.x * 256 + threadIdx.x;
  if (i < NN) {
    int e = excl[i] + part[i >> 8];
    excl[i] = e;
    cursor[i] = e;
  }
}

// ---------------- scatter + edge-row permute in ONE pass ----------------
__global__ __launch_bounds__(256) void scatter_permute_kernel(
    const int* __restrict__ senders, const int* __restrict__ recv,
    int* __restrict__ cursor, const float* __restrict__ edges,
    int* __restrict__ sendp, float* __restrict__ edgesP) {
  const int t = threadIdx.x;
  const int i = blockIdx.x * 64 + (t >> 2);
  if (i >= NE) return;
  const int sub = t & 3;
  int pos = 0;
  if (sub == 0) pos = atomicAdd(&cursor[recv[i]], 1);
  pos = __shfl(pos, (t & 63) & ~3);
  if (sub == 0) sendp[pos] = senders[i];
  *(float4*)&edgesP[(size_t)pos * 16 + sub * 4] =
      *(const float4*)&edges[(size_t)i * 16 + sub * 4];
}

// ---------------- Hs[v] = sum_{e->v} relu(edgesP_e @ W0 + b0), atomic-free ----------
// 4 independent accumulator chains over 4 edges/iter.
DEVFN void hs_accum2(const float4 x0, const float4 x1, const float4 x2,
                     const float4 x3, const float (&w)[16][2],
                     const float2 bb, float2& a) {
  float h0 = bb.x, h1 = bb.y;
  h0 += x0.x * w[0][0];  h1 += x0.x * w[0][1];
  h0 += x0.y * w[1][0];  h1 += x0.y * w[1][1];
  h0 += x0.z * w[2][0];  h1 += x0.z * w[2][1];
  h0 += x0.w * w[3][0];  h1 += x0.w * w[3][1];
  h0 += x1.x * w[4][0];  h1 += x1.x * w[4][1];
  h0 += x1.y * w[5][0];  h1 += x1.y * w[5][1];
  h0 += x1.z * w[6][0];  h1 += x1.z * w[6][1];
  h0 += x1.w * w[7][0];  h1 += x1.w * w[7][1];
  h0 += x2.x * w[8][0];  h1 += x2.x * w[8][1];
  h0 += x2.y * w[9][0];  h1 += x2.y * w[9][1];
  h0 += x2.z * w[10][0]; h1 += x2.z * w[10][1];
  h0 += x2.w * w[11][0]; h1 += x2.w * w[11][1];
  h0 += x3.x * w[12][0]; h1 += x3.x * w[12][1];
  h0 += x3.y * w[13][0]; h1 += x3.y * w[13][1];
  h0 += x3.z * w[14][0]; h1 += x3.z * w[14][1];
  h0 += x3.w * w[15][0]; h1 += x3.w * w[15][1];
  a.x += fmaxf(h0, 0.f);
  a.y += fmaxf(h1, 0.f);
}

__global__ __launch_bounds__(256) void hs_fused_kernel(
    const float* __restrict__ edgesP, const int* __restrict__ start,
    const int* __restrict__ endc, const float* __restrict__ W0,
    const float* __restrict__ b0, float* __restrict__ Hs) {
  const int t = threadIdx.x;
  const int v = blockIdx.x * 4 + (t >> 6);  // NN % 4 == 0
  const int lane = t & 63;
  const int c = lane * 2;
  float w[16][2];
#pragma unroll
  for (int k = 0; k < 16; ++k) {
    float2 ww = *(const float2*)&W0[(size_t)k * H + c];
    w[k][0] = ww.x; w[k][1] = ww.y;
  }
  const float2 bb = *(const float2*)&b0[c];
  float2 a0 = make_float2(0.f, 0.f);
  float2 a1 = make_float2(0.f, 0.f);
  float2 a2 = make_float2(0.f, 0.f);
  float2 a3 = make_float2(0.f, 0.f);
  int j = start[v];
  const int e = endc[v];
  for (; j + 3 < e; j += 4) {
    const float* x = &edgesP[(size_t)j * 16];
    float4 r0  = *(const float4*)(x + 0);
    float4 r1  = *(const float4*)(x + 4);
    float4 r2  = *(const float4*)(x + 8);
    float4 r3  = *(const float4*)(x + 12);
    float4 r4  = *(const float4*)(x + 16);
    float4 r5  = *(const float4*)(x + 20);
    float4 r6  = *(const float4*)(x + 24);
    float4 r7  = *(const float4*)(x + 28);
    float4 r8  = *(const float4*)(x + 32);
    float4 r9  = *(const float4*)(x + 36);
    float4 r10 = *(const float4*)(x + 40);
    float4 r11 = *(const float4*)(x + 44);
    float4 r12 = *(const float4*)(x + 48);
    float4 r13 = *(const float4*)(x + 52);
    float4 r14 = *(const float4*)(x + 56);
    float4 r15 = *(const float4*)(x + 60);
    hs_accum2(r0, r1, r2, r3, w, bb, a0);
    hs_accum2(r4, r5, r6, r7, w, bb, a1);
    hs_accum2(r8, r9, r10, r11, w, bb, a2);
    hs_accum2(r12, r13, r14, r15, w, bb, a3);
  }
  for (; j < e; ++j) {
    const float* x = &edgesP[(size_t)j * 16];
    float4 r0 = *(const float4*)(x + 0);
    float4 r1 = *(const float4*)(x + 4);
    float4 r2 = *(const float4*)(x + 8);
    float4 r3 = *(const float4*)(x + 12);
    hs_accum2(r0, r1, r2, r3, w, bb, a0);
  }
  float2 a = make_float2((a0.x + a1.x) + (a2.x + a3.x),
                         (a0.y + a1.y) + (a2.y + a3.y));
  *(float2*)&Hs[(size_t)v * H + c] = a;
}

// ---------------- B2pk[tile] = pack_C( Hs @ Wc2 + deg * bc2 )  (fused blin+packc) ----------
__global__ __launch_bounds__(128) void blinpack_kernel(
    const float* __restrict__ Hs, const float* __restrict__ Wc2,
    const float* __restrict__ bc2, const int* __restrict__ start,
    const int* __restrict__ endc, _Float16* __restrict__ B2pk) {
  __shared__ float xs[32 * 132];
  const int t = threadIdx.x;
  const int r0 = blockIdx.x * 32;
  {
    const int r = t & 31, q = t >> 5;
    int row = r0 + r;
    if (row >= NN) row = NN - 1;
    const float* src = &Hs[(size_t)row * H + q * 32];
#pragma unroll
    for (int j = 0; j < 8; ++j)
      *(float4*)&xs[r * 132 + q * 32 + j * 4] = *(const float4*)&src[j * 4];
  }
  __syncthreads();
  const int c0 = (t & 31) * 4;
  const int rbase = (t >> 5) * 8;
  const float4 bc4 = *(const float4*)&bc2[c0];
  float acc[8][4];
#pragma unroll
  for (int r = 0; r < 8; ++r) {
    int row = r0 + rbase + r;
    if (row >= NN) row = NN - 1;
    float deg = (float)(endc[row] - start[row]);
    acc[r][0] = deg * bc4.x; acc[r][1] = deg * bc4.y;
    acc[r][2] = deg * bc4.z; acc[r][3] = deg * bc4.w;
  }
  mm_block(&xs[rbase * 132], 132, H, Wc2, c0, acc);
  __syncthreads();  // all mm_block reads of xs done
#pragma unroll
  for (int r = 0; r < 8; ++r)
    *(float4*)&xs[(rbase + r) * 132 + c0] =
        make_float4(acc[r][0], acc[r][1], acc[r][2], acc[r][3]);
  __syncthreads();
  // pack into MFMA C layout (two 16-row tiles per block)
  const int half = t >> 6, l = t & 63;
  const int tile = blockIdx.x * 2 + half;
  const int rb = half * 16 + (l >> 4) * 4;
  const int col = l & 15;
  _Float16 tmp[32];
#pragma unroll
  for (int ct = 0; ct < 8; ++ct)
#pragma unroll
    for (int q = 0; q < 4; ++q)
      tmp[ct * 4 + q] = (_Float16)xs[(rb + q) * 132 + ct * 16 + col];
  _Float16* dst = &B2pk[((size_t)tile * 64 + l) * 32];
#pragma unroll
  for (int i = 0; i < 4; ++i)
    *(f16x8*)(dst + i * 8) = *(f16x8*)(tmp + i * 8);
}

// ---------------- per-pass gather, PHASED by column quarter for L2 residency ----------
// Phase p touches only cols [p*32, p*32+32) of n16: working set 50000*64B = 3.2 MB
// < 4 MiB per-XCD L2, so the ~12x per-row reuse hits L2 instead of the L3
// random-line wall. Phase-major block order clusters phases temporally.
// Wave = 1 node: 16 edge-slots x 4 lanes x 16B (f16x8) = 16 independent
// quarter-row loads per wave instruction; sendp[j0..j0+15] is one line.
__global__ __launch_bounds__(256) void gather_kernel(
    const _Float16* __restrict__ n16, const int* __restrict__ start,
    const int* __restrict__ endc, const int* __restrict__ sendp,
    _Float16* __restrict__ S) {
  const int t = threadIdx.x;
  const int nb = NN / 4;
  const int phase = blockIdx.x / nb;
  const int blk = blockIdx.x - phase * nb;
  const int wave = t >> 6, lane = t & 63;
  const int v = blk * 4 + wave;
  const int slot = lane >> 2;
  const int sub = lane & 3;
  const int c = phase * 32 + sub * 8;
  float a[8] = {0.f, 0.f, 0.f, 0.f, 0.f, 0.f, 0.f, 0.f};
  const int j0 = start[v];
  const int e = endc[v];
  {
    int j = j0 + slot;
    if (j < e) {
      int s = sendp[j];
      f16x8 p = *(const f16x8*)&n16[(size_t)s * H + c];
#pragma unroll
      for (int i = 0; i < 8; ++i) a[i] += (float)p[i];
    }
  }
  for (int j = j0 + 16 + slot; j < e; j += 16) {
    int s = sendp[j];
    f16x8 p = *(const f16x8*)&n16[(size_t)s * H + c];
#pragma unroll
    for (int i = 0; i < 8; ++i) a[i] += (float)p[i];
  }
#pragma unroll
  for (int i = 0; i < 8; ++i) {
    a[i] += __shfl_xor(a[i], 4);
    a[i] += __shfl_xor(a[i], 8);
    a[i] += __shfl_xor(a[i], 16);
    a[i] += __shfl_xor(a[i], 32);
  }
  if (lane < 4) {
    f16x8 o;
#pragma unroll
    for (int i = 0; i < 8; ++i) o[i] = (_Float16)a[i];
    *(f16x8*)&S[(size_t)v * H + c] = o;
  }
}

// ---------------- MFMA node update ----------------
// pre-act = n@W0t + S@Wf + B2 + b0 ; h = relu(pre-act)
// out = LN(h@W1 + n@Wn + b1)
__global__ __launch_bounds__(256) void node_mfma_kernel(
    const _Float16* __restrict__ n16, const _Float16* __restrict__ S16,
    const _Float16* __restrict__ B2pk,
    const _Float16* __restrict__ pkW0t, const _Float16* __restrict__ pkWf,
    const float* __restrict__ b0,
    const _Float16* __restrict__ pkW1, const _Float16* __restrict__ pkWn,
    const float* __restrict__ b1,
    const float* __restrict__ ln_g, const float* __restrict__ ln_b,
    _Float16* __restrict__ nout) {
  __shared__ _Float16 lds[4][16 * 136];
  const int t = threadIdx.x;
  const int wave = t >> 6, lane = t & 63;
  const int row0 = blockIdx.x * 64 + wave * 16;
  const int quad = lane >> 4, m16 = lane & 15;
  _Float16* hlds = &lds[wave][0];

  int arow = row0 + m16;
  if (arow >= NN) arow = NN - 1;
  const _Float16* nrow = &n16[(size_t)arow * H + quad * 8];
  const _Float16* srow = &S16[(size_t)arow * H + quad * 8];
  f16x8 an[4], as[4];
#pragma unroll
  for (int ks = 0; ks < 4; ++ks) {
    an[ks] = *(const f16x8*)(nrow + ks * 32);
    as[ks] = *(const f16x8*)(srow + ks * 32);
  }

  const int tile = blockIdx.x * 4 + wave;
  const _Float16* b2l = &B2pk[((size_t)tile * 64 + lane) * 32];
  f32x4 acc[8];
#pragma unroll
  for (int ct = 0; ct < 8; ++ct) {
    float bb = b0[ct * 16 + m16];
    f16x4 bv = *(const f16x4*)(b2l + ct * 4);
    acc[ct] = (f32x4){bb + (float)bv[0], bb + (float)bv[1],
                      bb + (float)bv[2], bb + (float)bv[3]};
  }
#pragma unroll
  for (int ks = 0; ks < 4; ++ks) {
    const _Float16* bp0 = pkW0t + ((size_t)ks * 8 * 64 + lane) * 8;
    const _Float16* bpf = pkWf + ((size_t)ks * 8 * 64 + lane) * 8;
#pragma unroll
    for (int ct = 0; ct < 8; ++ct) {
      f16x8 bw0 = *(const f16x8*)(bp0 + ct * 512);
      acc[ct] = __builtin_amdgcn_mfma_f32_16x16x32_f16(an[ks], bw0, acc[ct], 0, 0, 0);
      f16x8 bwf = *(const f16x8*)(bpf + ct * 512);
      acc[ct] = __builtin_amdgcn_mfma_f32_16x16x32_f16(as[ks], bwf, acc[ct], 0, 0, 0);
    }
  }
#pragma unroll
  for (int ct = 0; ct < 8; ++ct) {
#pragma unroll
    for (int q = 0; q < 4; ++q)
      hlds[(quad * 4 + q) * 136 + ct * 16 + m16] =
          (_Float16)fmaxf(acc[ct][q], 0.f);
  }
  __syncthreads();

  const _Float16* hrow = &hlds[m16 * 136 + quad * 8];
  f32x4 acc2[8];
#pragma unroll
  for (int ct = 0; ct < 8; ++ct) {
    float bb = b1[ct * 16 + m16];
    acc2[ct] = (f32x4){bb, bb, bb, bb};
  }
#pragma unroll
  for (int ks = 0; ks < 4; ++ks) {
    f16x8 ah = *(const f16x8*)(hrow + ks * 32);
    const _Float16* bp1 = pkW1 + ((size_t)ks * 8 * 64 + lane) * 8;
    const _Float16* bpn = pkWn + ((size_t)ks * 8 * 64 + lane) * 8;
#pragma unroll
    for (int ct = 0; ct < 8; ++ct) {
      f16x8 b1f = *(const f16x8*)(bp1 + ct * 512);
      acc2[ct] = __builtin_amdgcn_mfma_f32_16x16x32_f16(ah, b1f, acc2[ct], 0, 0, 0);
      f16x8 bnf = *(const f16x8*)(bpn + ct * 512);
      acc2[ct] = __builtin_amdgcn_mfma_f32_16x16x32_f16(an[ks], bnf, acc2[ct], 0, 0, 0);
    }
  }

  float gv[8], bv[8];
#pragma unroll
  for (int ct = 0; ct < 8; ++ct) {
    gv[ct] = ln_g[ct * 16 + m16];
    bv[ct] = ln_b[ct * 16 + m16];
  }
  __syncthreads();
#pragma unroll
  for (int q = 0; q < 4; ++q) {
    float s1 = 0.f, s2 = 0.f;
#pragma unroll
    for (int ct = 0; ct < 8; ++ct) {
      float v = acc2[ct][q];
      s1 += v; s2 += v * v;
    }
#pragma unroll
    for (int m = 1; m <= 8; m <<= 1) {
      s1 += __shfl_xor(s1, m);
      s2 += __shfl_xor(s2, m);
    }
    float mu = s1 * (1.f / 128.f);
    float var = s2 * (1.f / 128.f) - mu * mu;
    float rs = rsqrtf(var + LN_EPS);
#pragma unroll
    for (int ct = 0; ct < 8; ++ct) {
      float o = (acc2[ct][q] - mu) * rs * gv[ct] + bv[ct];
      hlds[(quad * 4 + q) * 136 + ct * 16 + m16] = (_Float16)o;
    }
  }
  __syncthreads();

  {
    int lr = lane >> 2;
    int cc = (lane & 3) * 32;
    const _Float16* src = &hlds[lr * 136 + cc];
    int orow = row0 + lr;
    if (orow < NN) {
      _Float16* dst = &nout[(size_t)orow * H + cc];
      *(f16x8*)(dst + 0)  = *(const f16x8*)(src + 0);
      *(f16x8*)(dst + 8)  = *(const f16x8*)(src + 8);
      *(f16x8*)(dst + 16) = *(const f16x8*)(src + 16);
      *(f16x8*)(dst + 24) = *(const f16x8*)(src + 24);
    }
  }
}

// ---------------- decoder (fp16 node input) ----------------
__global__ __launch_bounds__(128) void decode_kernel(
    const _Float16* __restrict__ n, const float* __restrict__ W0,
    const float* __restrict__ b0, const float* __restrict__ W1,
    const float* __restrict__ b1, float* __restrict__ out) {
  __shared__ float xs[32 * 132];
  __shared__ float hs[32 * 132];
  const int t = threadIdx.x;
  const int r0 = blockIdx.x * 32;
  {
    const int r = t & 31, q = t >> 5;
    int row = r0 + r;
    if (row >= NN) row = NN - 1;
    const _Float16* src = &n[(size_t)row * H + q * 32];
#pragma unroll
    for (int j = 0; j < 4; ++j) {
      f16x8 v8 = *(const f16x8*)&src[j * 8];
#pragma unroll
      for (int i = 0; i < 8; ++i)
        xs[r * 132 + q * 32 + j * 8 + i] = (float)v8[i];
    }
  }
  __syncthreads();
  const int c0 = (t & 31) * 4;
  const int rbase = (t >> 5) * 8;
  float acc[8][4];
  {
    float4 bb = *(const float4*)&b0[c0];
#pragma unroll
    for (int r = 0; r < 8; ++r) { acc[r][0] = bb.x; acc[r][1] = bb.y; acc[r][2] = bb.z; acc[r][3] = bb.w; }
  }
  mm_block(&xs[rbase * 132], 132, H, W0, c0, acc);
#pragma unroll
  for (int r = 0; r < 8; ++r) {
    float4 h;
    h.x = fmaxf(acc[r][0], 0.f); h.y = fmaxf(acc[r][1], 0.f);
    h.z = fmaxf(acc[r][2], 0.f); h.w = fmaxf(acc[r][3], 0.f);
    *(float4*)&hs[(rbase + r) * 132 + c0] = h;
  }
  __syncthreads();
  if (t < 64) {
    int r = t >> 1, c = t & 1;
    float s = b1[c];
    for (int k = 0; k < H; ++k) s += hs[r * 132 + k] * W1[k * 2 + c];
    int row = r0 + r;
    if (row < NN) out[(size_t)row * 2 + c] = s;
  }
}

__global__ __launch_bounds__(256) void zero_kernel(float4* __restrict__ p, int n4) {
  int i = blockIdx.x * 256 + threadIdx.x;
  if (i < n4) p[i] = make_float4(0.f, 0.f, 0.f, 0.f);
}

}  // namespace

extern "C" void kernel_launch(void* const* d_in, const int* in_sizes, int n_in,
                              void* d_out, int out_size, void* d_ws, size_t ws_size,
                              hipStream_t stream) {
  const float* nodes     = (const float*)d_in[0];
  const float* edges     = (const float*)d_in[1];
  const int*   senders   = (const int*)d_in[2];
  const int*   receivers = (const int*)d_in[3];
  const float* enc_n_W0 = (const float*)d_in[4];
  const float* enc_n_b0 = (const float*)d_in[5];
  const float* enc_n_W1 = (const float*)d_in[6];
  const float* enc_n_b1 = (const float*)d_in[7];
  const float* enc_e_W0 = (const float*)d_in[8];
  const float* enc_e_b0 = (const float*)d_in[9];
  const float* enc_e_W1 = (const float*)d_in[10];
  const float* enc_e_b1 = (const float*)d_in[11];
  const float* W_msg    = (const float*)d_in[12];
  const float* node_W0  = (const float*)d_in[13];
  const float* node_b0  = (const float*)d_in[14];
  const float* node_W1  = (const float*)d_in[15];
  const float* node_b1  = (const float*)d_in[16];
  const float* W_node   = (const float*)d_in[17];
  const float* ln_g     = (const float*)d_in[18];
  const float* ln_b     = (const float*)d_in[19];
  const float* dec_W0   = (const float*)d_in[20];
  const float* dec_b0   = (const float*)d_in[21];
  const float* dec_W1   = (const float*)d_in[22];
  const float* dec_b1   = (const float*)d_in[23];
  float* out = (float*)d_out;

  const float* Wt  = W_msg;                // rows 0..127 of W_msg
  const float* Wb  = W_msg + 128 * H;      // rows 128..255
  const float* W0t = node_W0;              // rows 0..127 of node_W0
  const float* W0b = node_W0 + 128 * H;    // rows 128..255

  const int mfmaBlocks = (NN + 63) / 64;   // 782
  const int nTiles     = mfmaBlocks * 4;

  // workspace layout
  float* Hs     = (float*)d_ws;                        // NN*H f32
  float* edgesP = Hs + (size_t)NN * H;                 // NE*16 f32 (38.4 MB)
  float* T      = edgesP + (size_t)NE * 16;            // 128*128 f32
  float* Wc2    = T + 128 * H;
  float* Wf32   = Wc2 + 128 * H;
  float* bc2    = Wf32 + 128 * H;                      // 128
  _Float16* n16a  = (_Float16*)(bc2 + 128);            // NN*H f16
  _Float16* n16b  = n16a + (size_t)NN * H;
  _Float16* S16   = n16b + (size_t)NN * H;
  _Float16* B2pk  = S16 + (size_t)NN * H;              // nTiles*64*32 f16
  _Float16* pkAll = B2pk + (size_t)nTiles * 64 * 32;   // 4 x 128*H f16 contiguous
  _Float16* pkW0t = pkAll;
  _Float16* pkWf  = pkAll + 1 * 128 * H;
  _Float16* pkW1  = pkAll + 2 * 128 * H;
  _Float16* pkWn  = pkAll + 3 * 128 * H;
  int* cnt    = (int*)(pkAll + 4 * 128 * H);
  int* excl   = cnt + NN;
  int* cursor = excl + NN;
  int* part   = cursor + NN;               // 256
  int* sendp  = part + 256;                // NE

  const int nodeBlocks = (NN + 31) / 32;     // 1563
  const int scanBlocks = (NN + 255) / 256;   // 196
  const int neBlocks   = (NE + 255) / 256;   // 2344

  // --- one-time: sort edges by receiver (scatter fused with 64B row permute) ---
  zero_kernel<<<(NN / 4 + 255) / 256, 256, 0, stream>>>((float4*)cnt, NN / 4);
  hist_kernel<<<neBlocks, 256, 0, stream>>>(receivers, cnt);
  scan1_kernel<<<scanBlocks, 256, 0, stream>>>(cnt, excl, part);
  scan2_kernel<<<1, 256, 0, stream>>>(part, scanBlocks);
  scan3_kernel<<<scanBlocks, 256, 0, stream>>>(excl, part, cursor);
  scatter_permute_kernel<<<(NE + 63) / 64, 256, 0, stream>>>(
      senders, receivers, cursor, edges, sendp, edgesP);

  // --- fold chains:  T = Wb@W0b; Wf = Wt@W0b;  then Wc2 = W1e@T, bc2 = b1e@T ---
  fold1_kernel<<<8, 128, 0, stream>>>(Wb, Wt, W0b, T, Wf32);
  fold2_kernel<<<5, 128, 0, stream>>>(enc_e_W1, enc_e_b1, T, Wc2, bc2);
  prepack4_kernel<<<dim3(4, 8, 4), 64, 0, stream>>>(W0t, Wf32, node_W1, W_node, pkAll);

  encoder_kernel<32><<<nodeBlocks, 128, 0, stream>>>(
      nodes, enc_n_W0, enc_n_b0, enc_n_W1, enc_n_b1, n16a, NN);
  hs_fused_kernel<<<NN / 4, 256, 0, stream>>>(
      edgesP, excl, cursor, enc_e_W0, enc_e_b0, Hs);
  blinpack_kernel<<<nodeBlocks, 128, 0, stream>>>(Hs, Wc2, bc2, excl, cursor, B2pk);

  // --- 5 weight-tied passes ---
  _Float16* ncur = n16a;
  _Float16* nnxt = n16b;
  for (int p = 0; p < 5; ++p) {
    gather_kernel<<<NN, 256, 0, stream>>>(ncur, excl, cursor, sendp, S16);
    node_mfma_kernel<<<mfmaBlocks, 256, 0, stream>>>(
        ncur, S16, B2pk, pkW0t, pkWf, node_b0, pkW1, pkWn, node_b1,
        ln_g, ln_b, nnxt);
    _Float16* tmp = ncur; ncur = nnxt; nnxt = tmp;
  }

  decode_kernel<<<nodeBlocks, 128, 0, stream>>>(ncur, dec_W0, dec_b0, dec_W1, dec_b1, out);
}

// Round 11
// 628.861 us; speedup vs baseline: 1.4823x; 1.4823x over previous
//
#include <hip/hip_runtime.h>

#define DEVFN __device__ __forceinline__

namespace {

constexpr int NN = 50000;   // nodes
constexpr int NE = 600000;  // edges
constexpr int H  = 128;
constexpr float LN_EPS = 1e-6f;

typedef _Float16 f16x8 __attribute__((ext_vector_type(8)));
typedef _Float16 f16x4 __attribute__((ext_vector_type(4)));
typedef float f32x4 __attribute__((ext_vector_type(4)));

// acc[8][4] += xs_tile(8 rows x K) @ W(K x 128) restricted to cols c0..c0+3.
DEVFN void mm_block(const float* xsrow, int pitch, int K,
                    const float* __restrict__ W, int c0, float (&acc)[8][4]) {
  for (int k = 0; k < K; k += 4) {
    float4 w0 = *(const float4*)(W + (size_t)(k + 0) * H + c0);
    float4 w1 = *(const float4*)(W + (size_t)(k + 1) * H + c0);
    float4 w2 = *(const float4*)(W + (size_t)(k + 2) * H + c0);
    float4 w3 = *(const float4*)(W + (size_t)(k + 3) * H + c0);
#pragma unroll
    for (int r = 0; r < 8; ++r) {
      float4 a = *(const float4*)(xsrow + r * pitch + k);
      acc[r][0] += a.x * w0.x; acc[r][0] += a.y * w1.x; acc[r][0] += a.z * w2.x; acc[r][0] += a.w * w3.x;
      acc[r][1] += a.x * w0.y; acc[r][1] += a.y * w1.y; acc[r][1] += a.z * w2.y; acc[r][1] += a.w * w3.y;
      acc[r][2] += a.x * w0.z; acc[r][2] += a.y * w1.z; acc[r][2] += a.z * w2.z; acc[r][2] += a.w * w3.z;
      acc[r][3] += a.x * w0.w; acc[r][3] += a.y * w1.w; acc[r][3] += a.z * w2.w; acc[r][3] += a.w * w3.w;
    }
  }
}

// shared fp32 linear body: y[r0..r0+32) = x @ W  (K=128, N=128)
DEVFN void linear_body(const float* __restrict__ x, const float* __restrict__ W,
                       float* __restrict__ y, int r0, int R, int t, float* xs) {
  {
    const int r = t & 31, q = t >> 5;
    int row = r0 + r;
    if (row >= R) row = R - 1;
    const float* src = &x[(size_t)row * H + q * 32];
#pragma unroll
    for (int j = 0; j < 8; ++j)
      *(float4*)&xs[r * 132 + q * 32 + j * 4] = *(const float4*)&src[j * 4];
  }
  __syncthreads();
  const int c0 = (t & 31) * 4;
  const int rbase = (t >> 5) * 8;
  float acc[8][4];
#pragma unroll
  for (int r = 0; r < 8; ++r) { acc[r][0] = 0.f; acc[r][1] = 0.f; acc[r][2] = 0.f; acc[r][3] = 0.f; }
  mm_block(&xs[rbase * 132], 132, H, W, c0, acc);
#pragma unroll
  for (int r = 0; r < 8; ++r) {
    int row = r0 + rbase + r;
    if (row < R)
      *(float4*)&y[(size_t)row * H + c0] =
          make_float4(acc[r][0], acc[r][1], acc[r][2], acc[r][3]);
  }
}

// ---------------- node encoder (2-layer MLP, ReLU between), fp16 out ----------------
template <int K_IN>
__global__ __launch_bounds__(128) void encoder_kernel(
    const float* __restrict__ x, const float* __restrict__ W0,
    const float* __restrict__ b0, const float* __restrict__ W1,
    const float* __restrict__ b1, _Float16* __restrict__ outp, int R) {
  constexpr int PIN = K_IN + 4;
  __shared__ float xs[32 * PIN];
  __shared__ float hs[32 * 132];
  const int t = threadIdx.x;
  const int r0 = blockIdx.x * 32;

  const int nvec = 32 * K_IN / 4;
  for (int i = t; i < nvec; i += 128) {
    int rr = i / (K_IN / 4);
    int kk = (i % (K_IN / 4)) * 4;
    int row = r0 + rr;
    float4 v = make_float4(0.f, 0.f, 0.f, 0.f);
    if (row < R) v = *(const float4*)&x[(size_t)row * K_IN + kk];
    *(float4*)&xs[rr * PIN + kk] = v;
  }
  __syncthreads();

  const int c0 = (t & 31) * 4;
  const int rbase = (t >> 5) * 8;
  float acc[8][4];
  {
    float4 bb = *(const float4*)&b0[c0];
#pragma unroll
    for (int r = 0; r < 8; ++r) { acc[r][0] = bb.x; acc[r][1] = bb.y; acc[r][2] = bb.z; acc[r][3] = bb.w; }
  }
  mm_block(&xs[rbase * PIN], PIN, K_IN, W0, c0, acc);
#pragma unroll
  for (int r = 0; r < 8; ++r) {
    float4 h;
    h.x = fmaxf(acc[r][0], 0.f); h.y = fmaxf(acc[r][1], 0.f);
    h.z = fmaxf(acc[r][2], 0.f); h.w = fmaxf(acc[r][3], 0.f);
    *(float4*)&hs[(rbase + r) * 132 + c0] = h;
  }
  __syncthreads();
  {
    float4 bb = *(const float4*)&b1[c0];
#pragma unroll
    for (int r = 0; r < 8; ++r) { acc[r][0] = bb.x; acc[r][1] = bb.y; acc[r][2] = bb.z; acc[r][3] = bb.w; }
  }
  mm_block(&hs[rbase * 132], 132, H, W1, c0, acc);
#pragma unroll
  for (int r = 0; r < 8; ++r) {
    int row = r0 + rbase + r;
    if (row < R) {
      f16x4 pk = {(_Float16)acc[r][0], (_Float16)acc[r][1],
                  (_Float16)acc[r][2], (_Float16)acc[r][3]};
      *(f16x4*)&outp[(size_t)row * H + c0] = pk;
    }
  }
}

// ---------------- fold stage 1: T = Wb@W0b (blocks 0-3), Wf = Wt@W0b (blocks 4-7) ----------------
__global__ __launch_bounds__(128) void fold1_kernel(
    const float* __restrict__ Wb, const float* __restrict__ Wt,
    const float* __restrict__ W0b, float* __restrict__ T,
    float* __restrict__ Wf) {
  __shared__ float xs[32 * 132];
  const float* x = (blockIdx.x < 4) ? Wb : Wt;
  float* y = (blockIdx.x < 4) ? T : Wf;
  linear_body(x, W0b, y, (blockIdx.x & 3) * 32, 128, threadIdx.x, xs);
}

// ---------------- fold stage 2: Wc2 = W1e@T (blocks 0-3), bc2 = b1e@T (block 4) ----------------
__global__ __launch_bounds__(128) void fold2_kernel(
    const float* __restrict__ W1e, const float* __restrict__ b1e,
    const float* __restrict__ T, float* __restrict__ Wc2,
    float* __restrict__ bc2) {
  __shared__ float xs[32 * 132];
  if (blockIdx.x < 4) {
    linear_body(W1e, T, Wc2, blockIdx.x * 32, 128, threadIdx.x, xs);
  } else {
    int j = threadIdx.x;
    float s = 0.f;
    for (int k = 0; k < H; ++k) s += b1e[k] * T[(size_t)k * H + j];
    bc2[j] = s;
  }
}

// ---------------- prepack 4 weight matrices -> MFMA B-fragment order, fp16 ----------------
__global__ __launch_bounds__(64) void prepack4_kernel(
    const float* __restrict__ s0, const float* __restrict__ s1,
    const float* __restrict__ s2, const float* __restrict__ s3,
    _Float16* __restrict__ pkBase) {
  const int z = blockIdx.z;
  const float* W = (z == 0) ? s0 : (z == 1) ? s1 : (z == 2) ? s2 : s3;
  _Float16* pk = pkBase + (size_t)z * 128 * H;
  const int ks = blockIdx.x, ct = blockIdx.y, l = threadIdx.x;
  const int kbase = ks * 32 + (l >> 4) * 8;
  const int col = ct * 16 + (l & 15);
  _Float16 tmp[8];
#pragma unroll
  for (int j = 0; j < 8; ++j)
    tmp[j] = (_Float16)W[(size_t)(kbase + j) * H + col];
  *(f16x8*)&pk[((size_t)((ks * 8 + ct) * 64) + l) * 8] = *(f16x8*)tmp;
}

// ---------------- prepack W0e[16 x 128] -> MFMA B-fragment (K padded 16->32, zeros) ----------
__global__ __launch_bounds__(64) void prepack_w0e_kernel(
    const float* __restrict__ W0e, _Float16* __restrict__ pk) {
  const int ct = blockIdx.x, l = threadIdx.x;
  const int quad = l >> 4;
  const int col = ct * 16 + (l & 15);
  _Float16 tmp[8];
#pragma unroll
  for (int j = 0; j < 8; ++j) {
    int k = quad * 8 + j;
    tmp[j] = (quad < 2) ? (_Float16)W0e[(size_t)k * H + col] : (_Float16)0.f;
  }
  *(f16x8*)&pk[((size_t)(ct * 64) + l) * 8] = *(f16x8*)tmp;
}

// ---------------- counting sort by receiver ----------------
__global__ __launch_bounds__(256) void hist_kernel(const int* __restrict__ recv,
                                                   int* __restrict__ cnt) {
  int i = blockIdx.x * 256 + threadIdx.x;
  if (i < NE) atomicAdd(&cnt[recv[i]], 1);
}

__global__ __launch_bounds__(256) void scan1_kernel(const int* __restrict__ cnt,
                                                    int* __restrict__ excl,
                                                    int* __restrict__ part) {
  __shared__ int s[256];
  int t = threadIdx.x;
  int i = blockIdx.x * 256 + t;
  int v = (i < NN) ? cnt[i] : 0;
  s[t] = v;
  __syncthreads();
  for (int off = 1; off < 256; off <<= 1) {
    int x = (t >= off) ? s[t - off] : 0;
    __syncthreads();
    s[t] += x;
    __syncthreads();
  }
  if (i < NN) excl[i] = s[t] - v;
  if (t == 255) part[blockIdx.x] = s[255];
}

__global__ __launch_bounds__(256) void scan2_kernel(int* __restrict__ part, int nb) {
  __shared__ int s[256];
  int t = threadIdx.x;
  int v = (t < nb) ? part[t] : 0;
  s[t] = v;
  __syncthreads();
  for (int off = 1; off < 256; off <<= 1) {
    int x = (t >= off) ? s[t - off] : 0;
    __syncthreads();
    s[t] += x;
    __syncthreads();
  }
  if (t < nb) part[t] = s[t] - v;
}

__global__ __launch_bounds__(256) void scan3_kernel(int* __restrict__ excl,
                                                    const int* __restrict__ part,
                                                    int* __restrict__ cursor) {
  int i = blockIdx.x * 256 + threadIdx.x;
  if (i < NN) {
    int e = excl[i] + part[i >> 8];
    excl[i] = e;
    cursor[i] = e;
  }
}

// ---------------- scatter + edge-row permute (fp16) in ONE pass ----------------
__global__ __launch_bounds__(256) void scatter_permute_kernel(
    const int* __restrict__ senders, const int* __restrict__ recv,
    int* __restrict__ cursor, const float* __restrict__ edges,
    int* __restrict__ sendp, _Float16* __restrict__ edgesP16) {
  const int t = threadIdx.x;
  const int i = blockIdx.x * 64 + (t >> 2);
  if (i >= NE) return;
  const int sub = t & 3;
  int pos = 0;
  if (sub == 0) pos = atomicAdd(&cursor[recv[i]], 1);
  pos = __shfl(pos, (t & 63) & ~3);
  if (sub == 0) sendp[pos] = senders[i];
  float4 v = *(const float4*)&edges[(size_t)i * 16 + sub * 4];
  f16x4 h = {(_Float16)v.x, (_Float16)v.y, (_Float16)v.z, (_Float16)v.w};
  *(f16x4*)&edgesP16[(size_t)pos * 16 + sub * 4] = h;
}

// ---------------- Hs[v] = sum_{e->v} relu(edgesP16_e @ W0e + b0e) via MFMA ----------
// One wave per node. A-tile: 16 receiver-sorted edges x K=16 (padded to 32 with
// zeros). Rows beyond deg: A zeroed AND relu output masked before accumulation
// (exact — the b0 bias enters only for real edges). Cross-quad shfl reduces the
// 16 rows; no atomics. Loads are 512 B contiguous per tile.
__global__ __launch_bounds__(256) void hs_mfma_kernel(
    const _Float16* __restrict__ edgesP16, const int* __restrict__ start,
    const int* __restrict__ endc, const _Float16* __restrict__ pkW0e,
    const float* __restrict__ b0e, float* __restrict__ Hs) {
  const int t = threadIdx.x;
  const int wave = t >> 6, lane = t & 63;
  const int v = blockIdx.x * 4 + wave;  // NN % 4 == 0
  const int quad = lane >> 4, m16 = lane & 15;
  const int j0 = start[v];
  const int deg = endc[v] - j0;

  float binit[8];
#pragma unroll
  for (int ct = 0; ct < 8; ++ct) binit[ct] = b0e[ct * 16 + m16];
  f16x8 bfrag[8];
#pragma unroll
  for (int ct = 0; ct < 8; ++ct)
    bfrag[ct] = *(const f16x8*)&pkW0e[((size_t)(ct * 64) + lane) * 8];

  float rsum[8][4];
#pragma unroll
  for (int ct = 0; ct < 8; ++ct)
#pragma unroll
    for (int q = 0; q < 4; ++q) rsum[ct][q] = 0.f;

  for (int base = 0; base < deg; base += 16) {
    f16x8 a = {};
    if (quad < 2 && base + m16 < deg)
      a = *(const f16x8*)&edgesP16[(size_t)(j0 + base + m16) * 16 + quad * 8];
#pragma unroll
    for (int ct = 0; ct < 8; ++ct) {
      f32x4 acc = (f32x4){binit[ct], binit[ct], binit[ct], binit[ct]};
      acc = __builtin_amdgcn_mfma_f32_16x16x32_f16(a, bfrag[ct], acc, 0, 0, 0);
#pragma unroll
      for (int q = 0; q < 4; ++q) {
        int row = quad * 4 + q;
        float hv = fmaxf(acc[q], 0.f);
        rsum[ct][q] += (base + row < deg) ? hv : 0.f;
      }
    }
  }
#pragma unroll
  for (int ct = 0; ct < 8; ++ct) {
    float s = (rsum[ct][0] + rsum[ct][1]) + (rsum[ct][2] + rsum[ct][3]);
    s += __shfl_xor(s, 16);
    s += __shfl_xor(s, 32);
    if (lane < 16) Hs[(size_t)v * H + ct * 16 + lane] = s;
  }
}

// ---------------- B2pk[tile] = pack_C( Hs @ Wc2 + deg * bc2 )  (fused blin+packc) ----------
__global__ __launch_bounds__(128) void blinpack_kernel(
    const float* __restrict__ Hs, const float* __restrict__ Wc2,
    const float* __restrict__ bc2, const int* __restrict__ start,
    const int* __restrict__ endc, _Float16* __restrict__ B2pk) {
  __shared__ float xs[32 * 132];
  const int t = threadIdx.x;
  const int r0 = blockIdx.x * 32;
  {
    const int r = t & 31, q = t >> 5;
    int row = r0 + r;
    if (row >= NN) row = NN - 1;
    const float* src = &Hs[(size_t)row * H + q * 32];
#pragma unroll
    for (int j = 0; j < 8; ++j)
      *(float4*)&xs[r * 132 + q * 32 + j * 4] = *(const float4*)&src[j * 4];
  }
  __syncthreads();
  const int c0 = (t & 31) * 4;
  const int rbase = (t >> 5) * 8;
  const float4 bc4 = *(const float4*)&bc2[c0];
  float acc[8][4];
#pragma unroll
  for (int r = 0; r < 8; ++r) {
    int row = r0 + rbase + r;
    if (row >= NN) row = NN - 1;
    float deg = (float)(endc[row] - start[row]);
    acc[r][0] = deg * bc4.x; acc[r][1] = deg * bc4.y;
    acc[r][2] = deg * bc4.z; acc[r][3] = deg * bc4.w;
  }
  mm_block(&xs[rbase * 132], 132, H, Wc2, c0, acc);
  __syncthreads();  // all mm_block reads of xs done
#pragma unroll
  for (int r = 0; r < 8; ++r)
    *(float4*)&xs[(rbase + r) * 132 + c0] =
        make_float4(acc[r][0], acc[r][1], acc[r][2], acc[r][3]);
  __syncthreads();
  // pack into MFMA C layout (two 16-row tiles per block)
  const int half = t >> 6, l = t & 63;
  const int tile = blockIdx.x * 2 + half;
  const int rb = half * 16 + (l >> 4) * 4;
  const int col = l & 15;
  _Float16 tmp[32];
#pragma unroll
  for (int ct = 0; ct < 8; ++ct)
#pragma unroll
    for (int q = 0; q < 4; ++q)
      tmp[ct * 4 + q] = (_Float16)xs[(rb + q) * 132 + ct * 16 + col];
  _Float16* dst = &B2pk[((size_t)tile * 64 + l) * 32];
#pragma unroll
  for (int i = 0; i < 4; ++i)
    *(f16x8*)(dst + i * 8) = *(f16x8*)(tmp + i * 8);
}

// ---------------- per-pass: S[v] = sum_{s in N(v)} n16[s]  (round-7 shape) ----------
// One WAVE per node. Lanes split 4 ways across edges (grp = lane>>4); each
// 16-lane group loads a full 256 B row (f16x8/lane). 2-deep unroll -> 8
// independent row loads in flight; dependent chain length ~deg/8.
__global__ __launch_bounds__(256) void gather_kernel(
    const _Float16* __restrict__ n16, const int* __restrict__ start,
    const int* __restrict__ endc, const int* __restrict__ sendp,
    _Float16* __restrict__ S) {
  const int t = threadIdx.x;
  const int v = blockIdx.x * 4 + (t >> 6);  // NN % 4 == 0
  const int lane = t & 63;
  const int grp = lane >> 4;
  const int c = (lane & 15) * 8;
  float a[8] = {0.f, 0.f, 0.f, 0.f, 0.f, 0.f, 0.f, 0.f};
  const int e = endc[v];
  int j = start[v];
  for (; j + 7 < e; j += 8) {
    int s0 = sendp[j + grp];
    int s1 = sendp[j + 4 + grp];
    f16x8 p0 = *(const f16x8*)&n16[(size_t)s0 * H + c];
    f16x8 p1 = *(const f16x8*)&n16[(size_t)s1 * H + c];
#pragma unroll
    for (int i = 0; i < 8; ++i) a[i] += (float)p0[i] + (float)p1[i];
  }
  for (; j < e; j += 4) {
    int jj = j + grp;
    if (jj < e) {
      int s0 = sendp[jj];
      f16x8 p0 = *(const f16x8*)&n16[(size_t)s0 * H + c];
#pragma unroll
      for (int i = 0; i < 8; ++i) a[i] += (float)p0[i];
    }
  }
#pragma unroll
  for (int i = 0; i < 8; ++i) {
    a[i] += __shfl_xor(a[i], 16);
    a[i] += __shfl_xor(a[i], 32);
  }
  if (lane < 16) {
    f16x8 o;
#pragma unroll
    for (int i = 0; i < 8; ++i) o[i] = (_Float16)a[i];
    *(f16x8*)&S[(size_t)v * H + c] = o;
  }
}

// ---------------- MFMA node update ----------------
// pre-act = n@W0t + S@Wf + B2 + b0 ; h = relu(pre-act)
// out = LN(h@W1 + n@Wn + b1)
__global__ __launch_bounds__(256) void node_mfma_kernel(
    const _Float16* __restrict__ n16, const _Float16* __restrict__ S16,
    const _Float16* __restrict__ B2pk,
    const _Float16* __restrict__ pkW0t, const _Float16* __restrict__ pkWf,
    const float* __restrict__ b0,
    const _Float16* __restrict__ pkW1, const _Float16* __restrict__ pkWn,
    const float* __restrict__ b1,
    const float* __restrict__ ln_g, const float* __restrict__ ln_b,
    _Float16* __restrict__ nout) {
  __shared__ _Float16 lds[4][16 * 136];
  const int t = threadIdx.x;
  const int wave = t >> 6, lane = t & 63;
  const int row0 = blockIdx.x * 64 + wave * 16;
  const int quad = lane >> 4, m16 = lane & 15;
  _Float16* hlds = &lds[wave][0];

  int arow = row0 + m16;
  if (arow >= NN) arow = NN - 1;
  const _Float16* nrow = &n16[(size_t)arow * H + quad * 8];
  const _Float16* srow = &S16[(size_t)arow * H + quad * 8];
  f16x8 an[4], as[4];
#pragma unroll
  for (int ks = 0; ks < 4; ++ks) {
    an[ks] = *(const f16x8*)(nrow + ks * 32);
    as[ks] = *(const f16x8*)(srow + ks * 32);
  }

  const int tile = blockIdx.x * 4 + wave;
  const _Float16* b2l = &B2pk[((size_t)tile * 64 + lane) * 32];
  f32x4 acc[8];
#pragma unroll
  for (int ct = 0; ct < 8; ++ct) {
    float bb = b0[ct * 16 + m16];
    f16x4 bv = *(const f16x4*)(b2l + ct * 4);
    acc[ct] = (f32x4){bb + (float)bv[0], bb + (float)bv[1],
                      bb + (float)bv[2], bb + (float)bv[3]};
  }
#pragma unroll
  for (int ks = 0; ks < 4; ++ks) {
    const _Float16* bp0 = pkW0t + ((size_t)ks * 8 * 64 + lane) * 8;
    const _Float16* bpf = pkWf + ((size_t)ks * 8 * 64 + lane) * 8;
#pragma unroll
    for (int ct = 0; ct < 8; ++ct) {
      f16x8 bw0 = *(const f16x8*)(bp0 + ct * 512);
      acc[ct] = __builtin_amdgcn_mfma_f32_16x16x32_f16(an[ks], bw0, acc[ct], 0, 0, 0);
      f16x8 bwf = *(const f16x8*)(bpf + ct * 512);
      acc[ct] = __builtin_amdgcn_mfma_f32_16x16x32_f16(as[ks], bwf, acc[ct], 0, 0, 0);
    }
  }
#pragma unroll
  for (int ct = 0; ct < 8; ++ct) {
#pragma unroll
    for (int q = 0; q < 4; ++q)
      hlds[(quad * 4 + q) * 136 + ct * 16 + m16] =
          (_Float16)fmaxf(acc[ct][q], 0.f);
  }
  __syncthreads();

  const _Float16* hrow = &hlds[m16 * 136 + quad * 8];
  f32x4 acc2[8];
#pragma unroll
  for (int ct = 0; ct < 8; ++ct) {
    float bb = b1[ct * 16 + m16];
    acc2[ct] = (f32x4){bb, bb, bb, bb};
  }
#pragma unroll
  for (int ks = 0; ks < 4; ++ks) {
    f16x8 ah = *(const f16x8*)(hrow + ks * 32);
    const _Float16* bp1 = pkW1 + ((size_t)ks * 8 * 64 + lane) * 8;
    const _Float16* bpn = pkWn + ((size_t)ks * 8 * 64 + lane) * 8;
#pragma unroll
    for (int ct = 0; ct < 8; ++ct) {
      f16x8 b1f = *(const f16x8*)(bp1 + ct * 512);
      acc2[ct] = __builtin_amdgcn_mfma_f32_16x16x32_f16(ah, b1f, acc2[ct], 0, 0, 0);
      f16x8 bnf = *(const f16x8*)(bpn + ct * 512);
      acc2[ct] = __builtin_amdgcn_mfma_f32_16x16x32_f16(an[ks], bnf, acc2[ct], 0, 0, 0);
    }
  }

  float gv[8], bv[8];
#pragma unroll
  for (int ct = 0; ct < 8; ++ct) {
    gv[ct] = ln_g[ct * 16 + m16];
    bv[ct] = ln_b[ct * 16 + m16];
  }
  __syncthreads();
#pragma unroll
  for (int q = 0; q < 4; ++q) {
    float s1 = 0.f, s2 = 0.f;
#pragma unroll
    for (int ct = 0; ct < 8; ++ct) {
      float v = acc2[ct][q];
      s1 += v; s2 += v * v;
    }
#pragma unroll
    for (int m = 1; m <= 8; m <<= 1) {
      s1 += __shfl_xor(s1, m);
      s2 += __shfl_xor(s2, m);
    }
    float mu = s1 * (1.f / 128.f);
    float var = s2 * (1.f / 128.f) - mu * mu;
    float rs = rsqrtf(var + LN_EPS);
#pragma unroll
    for (int ct = 0; ct < 8; ++ct) {
      float o = (acc2[ct][q] - mu) * rs * gv[ct] + bv[ct];
      hlds[(quad * 4 + q) * 136 + ct * 16 + m16] = (_Float16)o;
    }
  }
  __syncthreads();

  {
    int lr = lane >> 2;
    int cc = (lane & 3) * 32;
    const _Float16* src = &hlds[lr * 136 + cc];
    int orow = row0 + lr;
    if (orow < NN) {
      _Float16* dst = &nout[(size_t)orow * H + cc];
      *(f16x8*)(dst + 0)  = *(const f16x8*)(src + 0);
      *(f16x8*)(dst + 8)  = *(const f16x8*)(src + 8);
      *(f16x8*)(dst + 16) = *(const f16x8*)(src + 16);
      *(f16x8*)(dst + 24) = *(const f16x8*)(src + 24);
    }
  }
}

// ---------------- decoder (fp16 node input) ----------------
__global__ __launch_bounds__(128) void decode_kernel(
    const _Float16* __restrict__ n, const float* __restrict__ W0,
    const float* __restrict__ b0, const float* __restrict__ W1,
    const float* __restrict__ b1, float* __restrict__ out) {
  __shared__ float xs[32 * 132];
  __shared__ float hs[32 * 132];
  const int t = threadIdx.x;
  const int r0 = blockIdx.x * 32;
  {
    const int r = t & 31, q = t >> 5;
    int row = r0 + r;
    if (row >= NN) row = NN - 1;
    const _Float16* src = &n[(size_t)row * H + q * 32];
#pragma unroll
    for (int j = 0; j < 4; ++j) {
      f16x8 v8 = *(const f16x8*)&src[j * 8];
#pragma unroll
      for (int i = 0; i < 8; ++i)
        xs[r * 132 + q * 32 + j * 8 + i] = (float)v8[i];
    }
  }
  __syncthreads();
  const int c0 = (t & 31) * 4;
  const int rbase = (t >> 5) * 8;
  float acc[8][4];
  {
    float4 bb = *(const float4*)&b0[c0];
#pragma unroll
    for (int r = 0; r < 8; ++r) { acc[r][0] = bb.x; acc[r][1] = bb.y; acc[r][2] = bb.z; acc[r][3] = bb.w; }
  }
  mm_block(&xs[rbase * 132], 132, H, W0, c0, acc);
#pragma unroll
  for (int r = 0; r < 8; ++r) {
    float4 h;
    h.x = fmaxf(acc[r][0], 0.f); h.y = fmaxf(acc[r][1], 0.f);
    h.z = fmaxf(acc[r][2], 0.f); h.w = fmaxf(acc[r][3], 0.f);
    *(float4*)&hs[(rbase + r) * 132 + c0] = h;
  }
  __syncthreads();
  if (t < 64) {
    int r = t >> 1, c = t & 1;
    float s = b1[c];
    for (int k = 0; k < H; ++k) s += hs[r * 132 + k] * W1[k * 2 + c];
    int row = r0 + r;
    if (row < NN) out[(size_t)row * 2 + c] = s;
  }
}

__global__ __launch_bounds__(256) void zero_kernel(float4* __restrict__ p, int n4) {
  int i = blockIdx.x * 256 + threadIdx.x;
  if (i < n4) p[i] = make_float4(0.f, 0.f, 0.f, 0.f);
}

}  // namespace

extern "C" void kernel_launch(void* const* d_in, const int* in_sizes, int n_in,
                              void* d_out, int out_size, void* d_ws, size_t ws_size,
                              hipStream_t stream) {
  const float* nodes     = (const float*)d_in[0];
  const float* edges     = (const float*)d_in[1];
  const int*   senders   = (const int*)d_in[2];
  const int*   receivers = (const int*)d_in[3];
  const float* enc_n_W0 = (const float*)d_in[4];
  const float* enc_n_b0 = (const float*)d_in[5];
  const float* enc_n_W1 = (const float*)d_in[6];
  const float* enc_n_b1 = (const float*)d_in[7];
  const float* enc_e_W0 = (const float*)d_in[8];
  const float* enc_e_b0 = (const float*)d_in[9];
  const float* enc_e_W1 = (const float*)d_in[10];
  const float* enc_e_b1 = (const float*)d_in[11];
  const float* W_msg    = (const float*)d_in[12];
  const float* node_W0  = (const float*)d_in[13];
  const float* node_b0  = (const float*)d_in[14];
  const float* node_W1  = (const float*)d_in[15];
  const float* node_b1  = (const float*)d_in[16];
  const float* W_node   = (const float*)d_in[17];
  const float* ln_g     = (const float*)d_in[18];
  const float* ln_b     = (const float*)d_in[19];
  const float* dec_W0   = (const float*)d_in[20];
  const float* dec_b0   = (const float*)d_in[21];
  const float* dec_W1   = (const float*)d_in[22];
  const float* dec_b1   = (const float*)d_in[23];
  float* out = (float*)d_out;

  const float* Wt  = W_msg;                // rows 0..127 of W_msg
  const float* Wb  = W_msg + 128 * H;      // rows 128..255
  const float* W0t = node_W0;              // rows 0..127 of node_W0
  const float* W0b = node_W0 + 128 * H;    // rows 128..255

  const int mfmaBlocks = (NN + 63) / 64;   // 782
  const int nTiles     = mfmaBlocks * 4;

  // workspace layout
  float* Hs     = (float*)d_ws;                        // NN*H f32
  float* T      = Hs + (size_t)NN * H;                 // 128*128 f32
  float* Wc2    = T + 128 * H;
  float* Wf32   = Wc2 + 128 * H;
  float* bc2    = Wf32 + 128 * H;                      // 128
  _Float16* edgesP16 = (_Float16*)(bc2 + 128);         // NE*16 f16 (19.2 MB)
  _Float16* n16a  = edgesP16 + (size_t)NE * 16;        // NN*H f16
  _Float16* n16b  = n16a + (size_t)NN * H;
  _Float16* S16   = n16b + (size_t)NN * H;
  _Float16* B2pk  = S16 + (size_t)NN * H;              // nTiles*64*32 f16
  _Float16* pkAll = B2pk + (size_t)nTiles * 64 * 32;   // 4 x 128*H f16 contiguous
  _Float16* pkW0t = pkAll;
  _Float16* pkWf  = pkAll + 1 * 128 * H;
  _Float16* pkW1  = pkAll + 2 * 128 * H;
  _Float16* pkWn  = pkAll + 3 * 128 * H;
  _Float16* pkW0e = pkAll + 4 * 128 * H;               // 8*64*8 = 4096 f16
  int* cnt    = (int*)(pkW0e + 4096);
  int* excl   = cnt + NN;
  int* cursor = excl + NN;
  int* part   = cursor + NN;               // 256
  int* sendp  = part + 256;                // NE

  const int nodeBlocks = (NN + 31) / 32;     // 1563
  const int scanBlocks = (NN + 255) / 256;   // 196
  const int neBlocks   = (NE + 255) / 256;   // 2344

  // --- one-time: sort edges by receiver (scatter fused with fp16 row permute) ---
  zero_kernel<<<(NN / 4 + 255) / 256, 256, 0, stream>>>((float4*)cnt, NN / 4);
  hist_kernel<<<neBlocks, 256, 0, stream>>>(receivers, cnt);
  scan1_kernel<<<scanBlocks, 256, 0, stream>>>(cnt, excl, part);
  scan2_kernel<<<1, 256, 0, stream>>>(part, scanBlocks);
  scan3_kernel<<<scanBlocks, 256, 0, stream>>>(excl, part, cursor);
  scatter_permute_kernel<<<(NE + 63) / 64, 256, 0, stream>>>(
      senders, receivers, cursor, edges, sendp, edgesP16);

  // --- fold chains:  T = Wb@W0b; Wf = Wt@W0b;  then Wc2 = W1e@T, bc2 = b1e@T ---
  fold1_kernel<<<8, 128, 0, stream>>>(Wb, Wt, W0b, T, Wf32);
  fold2_kernel<<<5, 128, 0, stream>>>(enc_e_W1, enc_e_b1, T, Wc2, bc2);
  prepack4_kernel<<<dim3(4, 8, 4), 64, 0, stream>>>(W0t, Wf32, node_W1, W_node, pkAll);
  prepack_w0e_kernel<<<8, 64, 0, stream>>>(enc_e_W0, pkW0e);

  encoder_kernel<32><<<nodeBlocks, 128, 0, stream>>>(
      nodes, enc_n_W0, enc_n_b0, enc_n_W1, enc_n_b1, n16a, NN);
  hs_mfma_kernel<<<NN / 4, 256, 0, stream>>>(
      edgesP16, excl, cursor, pkW0e, enc_e_b0, Hs);
  blinpack_kernel<<<nodeBlocks, 128, 0, stream>>>(Hs, Wc2, bc2, excl, cursor, B2pk);

  // --- 5 weight-tied passes ---
  _Float16* ncur = n16a;
  _Float16* nnxt = n16b;
  for (int p = 0; p < 5; ++p) {
    gather_kernel<<<NN / 4, 256, 0, stream>>>(ncur, excl, cursor, sendp, S16);
    node_mfma_kernel<<<mfmaBlocks, 256, 0, stream>>>(
        ncur, S16, B2pk, pkW0t, pkWf, node_b0, pkW1, pkWn, node_b1,
        ln_g, ln_b, nnxt);
    _Float16* tmp = ncur; ncur = nnxt; nnxt = tmp;
  }

  decode_kernel<<<nodeBlocks, 128, 0, stream>>>(ncur, dec_W0, dec_b0, dec_W1, dec_b1, out);
}